// Round 1
// baseline (244.026 us; speedup 1.0000x reference)
//
#include <hip/hip_runtime.h>
#include <hip/hip_bf16.h>

#define NNODES 6144
#define FIN    128
#define FOUTC  64
#define NHEAD  2
#define ALPHA  0.2f
#define LN_EPS 1e-5f

typedef __attribute__((ext_vector_type(4))) float f32x4;
typedef __attribute__((ext_vector_type(8))) short short8;

// f32 -> bf16 bits, round-to-nearest-even
static __device__ __forceinline__ short f2bf(float x) {
    unsigned u = __float_as_uint(x);
    u = (u + 0x7fffu + ((u >> 16) & 1u)) >> 16;
    return (short)u;
}

// p = (uni ? 1 : (adj>0 ? exp(lrelu(s1+s2)) : 0)) * inv
static __device__ __forceinline__ float pcalc(float s1v, float s2v, int am,
                                              bool uni, float inv) {
    float e = s1v + s2v;
    e = fmaxf(e, ALPHA * e);              // leaky relu (exact for all finite e)
    float t = (am > 0) ? __expf(e) : 0.0f;
    t = uni ? 1.0f : t;
    return t * inv;
}

// K1: ht = h @ W per head; htbT[h][o][n] (bf16, transposed for MFMA B-frags);
//     s1[h][n] = ht . a1, s2[h][n] = ht . a2
__global__ __launch_bounds__(256) void gat_k1(const float* __restrict__ h,
        const float* __restrict__ W, const float* __restrict__ a,
        short* __restrict__ htbT, float* __restrict__ s1, float* __restrict__ s2) {
    __shared__ float hrow[4][FIN];
    const int wid = threadIdx.x >> 6, lane = threadIdx.x & 63;
    const int n = blockIdx.x * 4 + wid;
    hrow[wid][lane]      = h[(size_t)n * FIN + lane];
    hrow[wid][lane + 64] = h[(size_t)n * FIN + lane + 64];
    __syncthreads();
    float acc0 = 0.f, acc1 = 0.f;
    #pragma unroll 8
    for (int k = 0; k < FIN; ++k) {
        float hv = hrow[wid][k];
        acc0 = fmaf(hv, W[k * FOUTC + lane], acc0);            // head 0
        acc1 = fmaf(hv, W[(FIN + k) * FOUTC + lane], acc1);    // head 1
    }
    htbT[(size_t)lane * NNODES + n]           = f2bf(acc0);
    htbT[(size_t)(FOUTC + lane) * NNODES + n] = f2bf(acc1);
    // a layout: a[h][i][0] flat = a[h*128 + i]; a1 = [0:64), a2 = [64:128)
    float r00 = acc0 * a[lane];
    float r01 = acc0 * a[FOUTC + lane];
    float r10 = acc1 * a[2 * FOUTC + lane];
    float r11 = acc1 * a[3 * FOUTC + lane];
    #pragma unroll
    for (int off = 32; off; off >>= 1) {
        r00 += __shfl_xor(r00, off);
        r01 += __shfl_xor(r01, off);
        r10 += __shfl_xor(r10, off);
        r11 += __shfl_xor(r11, off);
    }
    if (lane == 0) {
        s1[n] = r00;          s2[n] = r01;
        s1[NNODES + n] = r10; s2[NNODES + n] = r11;
    }
}

// K2: psum[h][n] = sum_m exp(masked lrelu(s1[n]+s2[m]))  (unnormalized softmax denom)
__global__ __launch_bounds__(256) void gat_k2(const int* __restrict__ adj,
        const float* __restrict__ s1, const float* __restrict__ s2,
        float* __restrict__ psum) {
    const int n = blockIdx.x;
    const int t = threadIdx.x;
    const int wid = t >> 6, lane = t & 63;
    const int4* arow = (const int4*)(adj + (size_t)n * NNODES);
    const float4* s2h0 = (const float4*)(s2);
    const float4* s2h1 = (const float4*)(s2 + NNODES);
    const float s10 = s1[n], s11 = s1[NNODES + n];
    float sum0 = 0.f, sum1 = 0.f;
    #pragma unroll
    for (int i = 0; i < 6; ++i) {
        int c4 = t + i * 256;           // int4 index, < 1536
        int4 av = arow[c4];
        float4 sa = s2h0[c4];
        float4 sb = s2h1[c4];
        { float e = s10 + sa.x; e = fmaxf(e, ALPHA*e); sum0 += (av.x > 0) ? __expf(e) : 0.f; }
        { float e = s10 + sa.y; e = fmaxf(e, ALPHA*e); sum0 += (av.y > 0) ? __expf(e) : 0.f; }
        { float e = s10 + sa.z; e = fmaxf(e, ALPHA*e); sum0 += (av.z > 0) ? __expf(e) : 0.f; }
        { float e = s10 + sa.w; e = fmaxf(e, ALPHA*e); sum0 += (av.w > 0) ? __expf(e) : 0.f; }
        { float e = s11 + sb.x; e = fmaxf(e, ALPHA*e); sum1 += (av.x > 0) ? __expf(e) : 0.f; }
        { float e = s11 + sb.y; e = fmaxf(e, ALPHA*e); sum1 += (av.y > 0) ? __expf(e) : 0.f; }
        { float e = s11 + sb.z; e = fmaxf(e, ALPHA*e); sum1 += (av.z > 0) ? __expf(e) : 0.f; }
        { float e = s11 + sb.w; e = fmaxf(e, ALPHA*e); sum1 += (av.w > 0) ? __expf(e) : 0.f; }
    }
    #pragma unroll
    for (int off = 32; off; off >>= 1) {
        sum0 += __shfl_xor(sum0, off);
        sum1 += __shfl_xor(sum1, off);
    }
    __shared__ float red[2][4];
    if (lane == 0) { red[0][wid] = sum0; red[1][wid] = sum1; }
    __syncthreads();
    if (t == 0) {
        psum[n]          = red[0][0] + red[0][1] + red[0][2] + red[0][3];
        psum[NNODES + n] = red[1][0] + red[1][1] + red[1][2] + red[1][3];
    }
}

// K3: main fused pass. Block = 256 thr = 4 waves: wave -> (head = w&1, colsplit = w>>1).
// Each block: 16 rows, 1536-col chunk per wave. Per 32-col tile: compute p (att row
// values), store att (fp32), accumulate hp += att_bf16 @ htbT via mfma 16x16x32.
// A-frag: lane holds row (lane&15), k = 8*(lane>>4)+j (self-consistent relabeling).
__global__ __launch_bounds__(256) void gat_k3(const int* __restrict__ adj,
        const short* __restrict__ htbT, const float* __restrict__ s1,
        const float* __restrict__ s2, const float* __restrict__ psum,
        float* __restrict__ att, float* __restrict__ hpp) {
    const int w = threadIdx.x >> 6, lane = threadIdx.x & 63;
    const int hh = w & 1, cs = w >> 1;
    const int pc = blockIdx.x * 2 + cs;        // 0..3: which col quarter / partial
    const int n0 = blockIdx.y * 16;
    const int r = lane & 15, g = lane >> 4;
    const int node = n0 + r;
    const float s1v = s1[hh * NNODES + node];
    const float ps  = psum[hh * NNODES + node];
    const bool uni = !(ps > 0.f);              // degenerate all-masked row -> uniform
    const float inv = uni ? (1.0f / (float)NNODES) : (1.0f / ps);
    const float* s2h = s2 + hh * NNODES;
    const int* arow = adj + (size_t)node * NNODES;
    float* attrow = att + ((size_t)hh * NNODES + node) * NNODES;
    const short* bb = htbT + (size_t)hh * FOUTC * NNODES + (size_t)r * NNODES;
    const int cbase = pc * 1536;

    f32x4 acc0 = {0.f,0.f,0.f,0.f}, acc1 = {0.f,0.f,0.f,0.f};
    f32x4 acc2 = {0.f,0.f,0.f,0.f}, acc3 = {0.f,0.f,0.f,0.f};

    for (int it = 0; it < 48; ++it) {
        const int kb = cbase + it * 32 + g * 8;
        const int4* ap = (const int4*)(arow + kb);
        int4 av0 = ap[0], av1 = ap[1];
        float4 sa = *(const float4*)(s2h + kb);
        float4 sb = *(const float4*)(s2h + kb + 4);
        float p0 = pcalc(s1v, sa.x, av0.x, uni, inv);
        float p1 = pcalc(s1v, sa.y, av0.y, uni, inv);
        float p2 = pcalc(s1v, sa.z, av0.z, uni, inv);
        float p3 = pcalc(s1v, sa.w, av0.w, uni, inv);
        float p4 = pcalc(s1v, sb.x, av1.x, uni, inv);
        float p5 = pcalc(s1v, sb.y, av1.y, uni, inv);
        float p6 = pcalc(s1v, sb.z, av1.z, uni, inv);
        float p7 = pcalc(s1v, sb.w, av1.w, uni, inv);
        float4 st0 = {p0, p1, p2, p3};
        float4 st1 = {p4, p5, p6, p7};
        *(float4*)(attrow + kb)     = st0;
        *(float4*)(attrow + kb + 4) = st1;
        short8 af = { f2bf(p0), f2bf(p1), f2bf(p2), f2bf(p3),
                      f2bf(p4), f2bf(p5), f2bf(p6), f2bf(p7) };
        const short* bp = bb + kb;
        short8 b0 = *(const short8*)(bp);
        short8 b1 = *(const short8*)(bp + (size_t)16 * NNODES);
        short8 b2 = *(const short8*)(bp + (size_t)32 * NNODES);
        short8 b3 = *(const short8*)(bp + (size_t)48 * NNODES);
        acc0 = __builtin_amdgcn_mfma_f32_16x16x32_bf16(af, b0, acc0, 0, 0, 0);
        acc1 = __builtin_amdgcn_mfma_f32_16x16x32_bf16(af, b1, acc1, 0, 0, 0);
        acc2 = __builtin_amdgcn_mfma_f32_16x16x32_bf16(af, b2, acc2, 0, 0, 0);
        acc3 = __builtin_amdgcn_mfma_f32_16x16x32_bf16(af, b3, acc3, 0, 0, 0);
    }
    // C/D layout: out col o = nt*16 + (lane&15), out row = n0 + 4*(lane>>4) + reg
    float* hb = hpp + ((size_t)(pc * NHEAD + hh) * NNODES + (n0 + g * 4)) * FOUTC + r;
    #pragma unroll
    for (int reg = 0; reg < 4; ++reg) {
        hb[(size_t)reg * FOUTC +  0] = acc0[reg];
        hb[(size_t)reg * FOUTC + 16] = acc1[reg];
        hb[(size_t)reg * FOUTC + 32] = acc2[reg];
        hb[(size_t)reg * FOUTC + 48] = acc3[reg];
    }
}

// K4: sum 4 hp partials, layernorm over 128 features, write out
__global__ __launch_bounds__(256) void gat_k4(const float* __restrict__ hpp,
        const float* __restrict__ gamma, const float* __restrict__ beta,
        float* __restrict__ out) {
    const int wid = threadIdx.x >> 6, lane = threadIdx.x & 63;
    const int n = blockIdx.x * 4 + wid;
    float v0 = 0.f, v1 = 0.f;
    #pragma unroll
    for (int p = 0; p < 4; ++p) {
        v0 += hpp[((size_t)(p * NHEAD + 0) * NNODES + n) * FOUTC + lane];
        v1 += hpp[((size_t)(p * NHEAD + 1) * NNODES + n) * FOUTC + lane];
    }
    float s = v0 + v1;
    #pragma unroll
    for (int off = 32; off; off >>= 1) s += __shfl_xor(s, off);
    const float mu = s * (1.0f / 128.0f);
    const float d0 = v0 - mu, d1 = v1 - mu;
    float q = d0 * d0 + d1 * d1;
    #pragma unroll
    for (int off = 32; off; off >>= 1) q += __shfl_xor(q, off);
    const float rstd = 1.0f / sqrtf(q * (1.0f / 128.0f) + LN_EPS);
    out[(size_t)n * 128 + lane]      = d0 * rstd * gamma[lane] + beta[lane];
    out[(size_t)n * 128 + 64 + lane] = d1 * rstd * gamma[64 + lane] + beta[64 + lane];
}

extern "C" void kernel_launch(void* const* d_in, const int* in_sizes, int n_in,
                              void* d_out, int out_size, void* d_ws, size_t ws_size,
                              hipStream_t stream) {
    const float* h     = (const float*)d_in[0];
    const int*   adj   = (const int*)d_in[1];
    const float* W     = (const float*)d_in[2];
    const float* a     = (const float*)d_in[3];
    const float* gamma = (const float*)d_in[4];
    const float* beta  = (const float*)d_in[5];
    float* out = (float*)d_out;
    float* att = out + (size_t)NNODES * (NHEAD * FOUTC);   // out first, then att

    char* ws = (char*)d_ws;
    short* htbT = (short*)ws;                               // 2*64*6144*2  = 1,572,864 B
    float* s1   = (float*)(ws + 1572864);                   // 49,152 B
    float* s2   = (float*)(ws + 1572864 + 49152);           // 49,152 B
    float* psum = (float*)(ws + 1572864 + 2 * 49152);       // 49,152 B
    float* hpp  = (float*)(ws + 1572864 + 3 * 49152);       // 4*2*6144*64*4 = 12,582,912 B

    gat_k1<<<NNODES / 4, 256, 0, stream>>>(h, W, a, htbT, s1, s2);
    gat_k2<<<NNODES, 256, 0, stream>>>(adj, s1, s2, psum);
    gat_k3<<<dim3(2, NNODES / 16), 256, 0, stream>>>(adj, htbT, s1, s2, psum, att, hpp);
    gat_k4<<<NNODES / 4, 256, 0, stream>>>(hpp, gamma, beta, out);
}

// Round 2
// 170.917 us; speedup vs baseline: 1.4277x; 1.4277x over previous
//
#include <hip/hip_runtime.h>
#include <hip/hip_bf16.h>

#define NNODES 6144
#define FIN    128
#define FOUTC  64
#define NHEAD  2
#define ALPHA  0.2f
#define LN_EPS 1e-5f
#define MASKW  192                      // u32 words per row (6144/32)

typedef __attribute__((ext_vector_type(4))) float f32x4;
typedef __attribute__((ext_vector_type(8))) short short8;

// f32 -> bf16 bits, round-to-nearest-even
static __device__ __forceinline__ short f2bf(float x) {
    unsigned u = __float_as_uint(x);
    u = (u + 0x7fffu + ((u >> 16) & 1u)) >> 16;
    return (short)u;
}

// p = (uni ? 1 : (bit ? exp(lrelu(s1+s2)) : 0)) * inv
static __device__ __forceinline__ float pcalc(float s1v, float s2v, unsigned bit,
                                              bool uni, float inv) {
    float e = s1v + s2v;
    e = fmaxf(e, ALPHA * e);              // leaky relu
    float t = bit ? __expf(e) : 0.0f;
    t = uni ? 1.0f : t;
    return t * inv;
}

// K1: ht = h @ W per head; htbT[h][o][n] (bf16, transposed for MFMA B-frags);
//     s1[h][n] = ht . a1, s2[h][n] = ht . a2
__global__ __launch_bounds__(256) void gat_k1(const float* __restrict__ h,
        const float* __restrict__ W, const float* __restrict__ a,
        short* __restrict__ htbT, float* __restrict__ s1, float* __restrict__ s2) {
    __shared__ float hrow[4][FIN];
    const int wid = threadIdx.x >> 6, lane = threadIdx.x & 63;
    const int n = blockIdx.x * 4 + wid;
    hrow[wid][lane]      = h[(size_t)n * FIN + lane];
    hrow[wid][lane + 64] = h[(size_t)n * FIN + lane + 64];
    __syncthreads();
    float acc0 = 0.f, acc1 = 0.f;
    #pragma unroll 8
    for (int k = 0; k < FIN; ++k) {
        float hv = hrow[wid][k];
        acc0 = fmaf(hv, W[k * FOUTC + lane], acc0);            // head 0
        acc1 = fmaf(hv, W[(FIN + k) * FOUTC + lane], acc1);    // head 1
    }
    htbT[(size_t)lane * NNODES + n]           = f2bf(acc0);
    htbT[(size_t)(FOUTC + lane) * NNODES + n] = f2bf(acc1);
    float r00 = acc0 * a[lane];
    float r01 = acc0 * a[FOUTC + lane];
    float r10 = acc1 * a[2 * FOUTC + lane];
    float r11 = acc1 * a[3 * FOUTC + lane];
    #pragma unroll
    for (int off = 32; off; off >>= 1) {
        r00 += __shfl_xor(r00, off);
        r01 += __shfl_xor(r01, off);
        r10 += __shfl_xor(r10, off);
        r11 += __shfl_xor(r11, off);
    }
    if (lane == 0) {
        s1[n] = r00;          s2[n] = r01;
        s1[NNODES + n] = r10; s2[NNODES + n] = r11;
    }
}

// K2: psum[h][n] = softmax denominator; ALSO packs adj row into a bitmask
// (1 bit per col, u32 word w covers cols [32w,32w+32), bit b = col 32w+b).
__global__ __launch_bounds__(256) void gat_k2(const int* __restrict__ adj,
        const float* __restrict__ s1, const float* __restrict__ s2,
        float* __restrict__ psum, unsigned* __restrict__ mask32) {
    const int n = blockIdx.x;
    const int t = threadIdx.x;
    const int wid = t >> 6, lane = t & 63;
    const int4* arow = (const int4*)(adj + (size_t)n * NNODES);
    const float4* s2h0 = (const float4*)(s2);
    const float4* s2h1 = (const float4*)(s2 + NNODES);
    const float s10 = s1[n], s11 = s1[NNODES + n];
    float sum0 = 0.f, sum1 = 0.f;
    unsigned* mrow = mask32 + (size_t)n * MASKW;
    #pragma unroll
    for (int i = 0; i < 6; ++i) {
        int c4 = t + i * 256;           // int4 index; lane's cols = 4*c4 .. +3
        int4 av = arow[c4];
        float4 sa = s2h0[c4];
        float4 sb = s2h1[c4];
        { float e = s10 + sa.x; e = fmaxf(e, ALPHA*e); sum0 += (av.x > 0) ? __expf(e) : 0.f; }
        { float e = s10 + sa.y; e = fmaxf(e, ALPHA*e); sum0 += (av.y > 0) ? __expf(e) : 0.f; }
        { float e = s10 + sa.z; e = fmaxf(e, ALPHA*e); sum0 += (av.z > 0) ? __expf(e) : 0.f; }
        { float e = s10 + sa.w; e = fmaxf(e, ALPHA*e); sum0 += (av.w > 0) ? __expf(e) : 0.f; }
        { float e = s11 + sb.x; e = fmaxf(e, ALPHA*e); sum1 += (av.x > 0) ? __expf(e) : 0.f; }
        { float e = s11 + sb.y; e = fmaxf(e, ALPHA*e); sum1 += (av.y > 0) ? __expf(e) : 0.f; }
        { float e = s11 + sb.z; e = fmaxf(e, ALPHA*e); sum1 += (av.z > 0) ? __expf(e) : 0.f; }
        { float e = s11 + sb.w; e = fmaxf(e, ALPHA*e); sum1 += (av.w > 0) ? __expf(e) : 0.f; }
        // ---- bitmask pack: nibble per lane, OR-combine across 8-lane groups ----
        unsigned nib = (unsigned)(av.x > 0) | ((unsigned)(av.y > 0) << 1)
                     | ((unsigned)(av.z > 0) << 2) | ((unsigned)(av.w > 0) << 3);
        unsigned v = nib << ((lane & 7) * 4);
        v |= (unsigned)__shfl_xor((int)v, 1);
        v |= (unsigned)__shfl_xor((int)v, 2);
        v |= (unsigned)__shfl_xor((int)v, 4);
        if ((lane & 7) == 0)
            mrow[i * 32 + wid * 8 + (lane >> 3)] = v;   // word covers 32 contiguous cols
    }
    #pragma unroll
    for (int off = 32; off; off >>= 1) {
        sum0 += __shfl_xor(sum0, off);
        sum1 += __shfl_xor(sum1, off);
    }
    __shared__ float red[2][4];
    if (lane == 0) { red[0][wid] = sum0; red[1][wid] = sum1; }
    __syncthreads();
    if (t == 0) {
        psum[n]          = red[0][0] + red[0][1] + red[0][2] + red[0][3];
        psum[NNODES + n] = red[1][0] + red[1][1] + red[1][2] + red[1][3];
    }
}

// K3: main fused pass. Block = 256 thr = 4 waves: wave -> (head = w&1, colsplit = w>>1).
// Each block: 16 rows; col chunk pc = blockIdx.x*2+cs of `iters`*32 cols. Per 32-col
// tile: compute p from bitmask (L2) + s1/s2, nt-store att (fp32), accumulate
// hp += att_bf16 @ htbT via mfma 16x16x32.
__global__ __launch_bounds__(256) void gat_k3(const unsigned* __restrict__ mask32,
        const short* __restrict__ htbT, const float* __restrict__ s1,
        const float* __restrict__ s2, const float* __restrict__ psum,
        float* __restrict__ att, float* __restrict__ hpp, int iters) {
    const int w = threadIdx.x >> 6, lane = threadIdx.x & 63;
    const int hh = w & 1, cs = w >> 1;
    const int pc = blockIdx.x * 2 + cs;        // chunk index
    const int n0 = blockIdx.y * 16;
    const int r = lane & 15, g = lane >> 4;
    const int node = n0 + r;
    const float s1v = s1[hh * NNODES + node];
    const float ps  = psum[hh * NNODES + node];
    const bool uni = !(ps > 0.f);              // degenerate all-masked row -> uniform
    const float inv = uni ? (1.0f / (float)NNODES) : (1.0f / ps);
    const float* s2h = s2 + hh * NNODES;
    const unsigned* mrow = mask32 + (size_t)node * MASKW + pc * iters;
    float* attrow = att + ((size_t)hh * NNODES + node) * NNODES;
    const short* bb = htbT + (size_t)hh * FOUTC * NNODES + (size_t)r * NNODES;
    const int cbase = pc * iters * 32;

    f32x4 acc0 = {0.f,0.f,0.f,0.f}, acc1 = {0.f,0.f,0.f,0.f};
    f32x4 acc2 = {0.f,0.f,0.f,0.f}, acc3 = {0.f,0.f,0.f,0.f};

    #pragma unroll 2
    for (int it = 0; it < iters; ++it) {
        const int kb = cbase + it * 32 + g * 8;
        const unsigned mb = (mrow[it] >> (g * 8)) & 0xffu;   // 8 adjacency bits
        float4 sa = *(const float4*)(s2h + kb);
        float4 sb = *(const float4*)(s2h + kb + 4);
        float p0 = pcalc(s1v, sa.x, mb & 1u,         uni, inv);
        float p1 = pcalc(s1v, sa.y, mb & 2u,         uni, inv);
        float p2 = pcalc(s1v, sa.z, mb & 4u,         uni, inv);
        float p3 = pcalc(s1v, sa.w, mb & 8u,         uni, inv);
        float p4 = pcalc(s1v, sb.x, mb & 16u,        uni, inv);
        float p5 = pcalc(s1v, sb.y, mb & 32u,        uni, inv);
        float p6 = pcalc(s1v, sb.z, mb & 64u,        uni, inv);
        float p7 = pcalc(s1v, sb.w, mb & 128u,       uni, inv);
        f32x4 st0 = {p0, p1, p2, p3};
        f32x4 st1 = {p4, p5, p6, p7};
        __builtin_nontemporal_store(st0, (f32x4*)(attrow + kb));
        __builtin_nontemporal_store(st1, (f32x4*)(attrow + kb + 4));
        short8 af = { f2bf(p0), f2bf(p1), f2bf(p2), f2bf(p3),
                      f2bf(p4), f2bf(p5), f2bf(p6), f2bf(p7) };
        const short* bp = bb + kb;
        short8 b0 = *(const short8*)(bp);
        short8 b1 = *(const short8*)(bp + (size_t)16 * NNODES);
        short8 b2 = *(const short8*)(bp + (size_t)32 * NNODES);
        short8 b3 = *(const short8*)(bp + (size_t)48 * NNODES);
        acc0 = __builtin_amdgcn_mfma_f32_16x16x32_bf16(af, b0, acc0, 0, 0, 0);
        acc1 = __builtin_amdgcn_mfma_f32_16x16x32_bf16(af, b1, acc1, 0, 0, 0);
        acc2 = __builtin_amdgcn_mfma_f32_16x16x32_bf16(af, b2, acc2, 0, 0, 0);
        acc3 = __builtin_amdgcn_mfma_f32_16x16x32_bf16(af, b3, acc3, 0, 0, 0);
    }
    // C/D layout: out col o = nt*16 + (lane&15), out row = n0 + 4*(lane>>4) + reg
    float* hb = hpp + ((size_t)(pc * NHEAD + hh) * NNODES + (n0 + g * 4)) * FOUTC + r;
    #pragma unroll
    for (int reg = 0; reg < 4; ++reg) {
        hb[(size_t)reg * FOUTC +  0] = acc0[reg];
        hb[(size_t)reg * FOUTC + 16] = acc1[reg];
        hb[(size_t)reg * FOUTC + 32] = acc2[reg];
        hb[(size_t)reg * FOUTC + 48] = acc3[reg];
    }
}

// K4: sum nchunk hp partials per head, layernorm over 128 features, write out
__global__ __launch_bounds__(256) void gat_k4(const float* __restrict__ hpp,
        const float* __restrict__ gamma, const float* __restrict__ beta,
        float* __restrict__ out, int nchunk) {
    const int wid = threadIdx.x >> 6, lane = threadIdx.x & 63;
    const int n = blockIdx.x * 4 + wid;
    float v0 = 0.f, v1 = 0.f;
    for (int p = 0; p < nchunk; ++p) {
        v0 += hpp[((size_t)(p * NHEAD + 0) * NNODES + n) * FOUTC + lane];
        v1 += hpp[((size_t)(p * NHEAD + 1) * NNODES + n) * FOUTC + lane];
    }
    float s = v0 + v1;
    #pragma unroll
    for (int off = 32; off; off >>= 1) s += __shfl_xor(s, off);
    const float mu = s * (1.0f / 128.0f);
    const float d0 = v0 - mu, d1 = v1 - mu;
    float q = d0 * d0 + d1 * d1;
    #pragma unroll
    for (int off = 32; off; off >>= 1) q += __shfl_xor(q, off);
    const float rstd = 1.0f / sqrtf(q * (1.0f / 128.0f) + LN_EPS);
    out[(size_t)n * 128 + lane]      = d0 * rstd * gamma[lane] + beta[lane];
    out[(size_t)n * 128 + 64 + lane] = d1 * rstd * gamma[64 + lane] + beta[64 + lane];
}

extern "C" void kernel_launch(void* const* d_in, const int* in_sizes, int n_in,
                              void* d_out, int out_size, void* d_ws, size_t ws_size,
                              hipStream_t stream) {
    const float* h     = (const float*)d_in[0];
    const int*   adj   = (const int*)d_in[1];
    const float* W     = (const float*)d_in[2];
    const float* a     = (const float*)d_in[3];
    const float* gamma = (const float*)d_in[4];
    const float* beta  = (const float*)d_in[5];
    float* out = (float*)d_out;
    float* att = out + (size_t)NNODES * (NHEAD * FOUTC);   // out first, then att

    char* ws = (char*)d_ws;
    short*    htbT   = (short*)ws;                          // 1,572,864 B
    float*    s1     = (float*)(ws + 1572864);              // 49,152 B
    float*    s2     = (float*)(ws + 1621 * 1024 - 1024 + 0);// (computed below instead)
    // explicit offsets:
    s1   = (float*)(ws + 1572864);
    float* s2p   = (float*)(ws + 1572864 + 49152);
    float* psum  = (float*)(ws + 1572864 + 2 * 49152);
    unsigned* mask32 = (unsigned*)(ws + 1572864 + 3 * 49152);        // 4,718,592 B
    char* hpp_base = ws + 1572864 + 3 * 49152 + 4718592;             // = 6,438,912
    size_t avail = (ws_size > 6438912) ? ws_size - 6438912 : 0;
    const size_t per_chunk = (size_t)NHEAD * NNODES * FOUTC * 4;     // 3,145,728 B
    int nchunk = 2;
    if (avail >= 8 * per_chunk)      nchunk = 8;
    else if (avail >= 4 * per_chunk) nchunk = 4;
    float* hpp = (float*)hpp_base;
    const int iters = NNODES / nchunk / 32;

    gat_k1<<<NNODES / 4, 256, 0, stream>>>(h, W, a, htbT, s1, s2p);
    gat_k2<<<NNODES, 256, 0, stream>>>(adj, s1, s2p, psum, mask32);
    gat_k3<<<dim3(nchunk / 2, NNODES / 16), 256, 0, stream>>>(mask32, htbT, s1, s2p,
                                                              psum, att, hpp, iters);
    gat_k4<<<NNODES / 4, 256, 0, stream>>>(hpp, gamma, beta, out, nchunk);
}